// Round 12
// baseline (295.670 us; speedup 1.0000x reference)
//
#include <hip/hip_runtime.h>
#include <math.h>

#define L 1024
#define NB 8
#define D 768
#define NEGV (-9.0e15f)
#define SCALE 0.036084391824351615f  // 1/sqrt(768)

typedef unsigned short u16;
typedef __attribute__((ext_vector_type(8))) short short8;
typedef __attribute__((ext_vector_type(4))) float float4v;
#define MFMA_BF16 __builtin_amdgcn_mfma_f32_16x16x32_bf16

__device__ __forceinline__ float b2f(u16 u) {
    union { unsigned int i; float f; } v; v.i = ((unsigned int)u) << 16; return v.f;
}
__device__ __forceinline__ u16 f2b(float f) {
    union { float fv; unsigned int i; } v; v.fv = f;
    unsigned int x = v.i;
    x += 0x7fffu + ((x >> 16) & 1u);   // RNE
    return (u16)(x >> 16);
}

template<int F32>
__device__ __forceinline__ float4 ld4(const void* p, size_t idx) {
    if (F32) return *(const float4*)((const float*)p + idx);
    ushort4 v = *(const ushort4*)((const u16*)p + idx);
    return make_float4(b2f(v.x), b2f(v.y), b2f(v.z), b2f(v.w));
}
template<int F32>
__device__ __forceinline__ float ld1(const void* p, size_t idx) {
    if (F32) return ((const float*)p)[idx];
    return b2f(((const u16*)p)[idx]);
}
__device__ __forceinline__ int ldid(const int* p, size_t idx, int is64) {
    return is64 ? p[idx * 2] : p[idx];
}

// ---------------- workspace layout (bytes) ----------------
#define WS_FLAG  ((size_t)0)
#define WS_SEP   ((size_t)64)
#define WS_C0    ((size_t)128)        // 1 f32 (con)
#define WS_Z0    ((size_t)192)        // 3*D f32
#define WS_W1    ((size_t)9472)       // D f32 (con only)
#define WS_GATE  ((size_t)18752)
#define WS_CSUP  ((size_t)51520)
#define WS_CREP  ((size_t)84288)
#define WS_AF    ((size_t)117056)
#define WS_WREP  ((size_t)141632)
#define WS_WSUP  ((size_t)166208)
#define WS_HACC  ((size_t)190784)
#define WS_ALOG  ((size_t)215360)
#define WS_T     ((size_t)248128)     // NB*512 f32 (con t only)
#define WS_OACC  ((size_t)303104)
#define WS_XB    ((size_t)524288)     // NB*L*D bf16 -> 13107200
#define WS_Z     ((size_t)13107200)   // 3*NB*512*D bf16 -> 31981568
#define WS_SSUP  ((size_t)31981568)   // NB*512*L bf16 -> 40370176
#define WS_SCMB  ((size_t)40370176)   // NB*512*L bf16 -> 48758784
#define WS_M     WS_SCMB              // 3*D*D bf16 (dead before kS writes scmb)

struct PP { const void* W[6]; const void* b[6]; };

// ---------------- detect dtypes (standalone, proven) ----------------
__global__ __launch_bounds__(128) void kdetect(const void* x, const void* ids, int* flag) {
    __shared__ int cnt[2];
    int tid = threadIdx.x;
    if (tid == 0) { cnt[0] = 0; cnt[1] = 0; }
    __syncthreads();
    if (tid < 64) {
        u16 u = ((const u16*)x)[tid * 2];
        int e = (u >> 7) & 0xFF;
        if (e >= 100 && e <= 140) atomicAdd(&cnt[0], 1);
    } else {
        int v = ((const int*)ids)[(tid - 64) * 2 + 1];
        if (v != 0) atomicAdd(&cnt[1], 1);
    }
    __syncthreads();
    if (tid == 0) {
        flag[0] = (cnt[0] < 32) ? 1 : 0;   // 1 => floats are f32
        flag[1] = (cnt[1] == 0) ? 1 : 0;   // 1 => ids are int64
    }
}

// ---------------- kbias_row: y<3 z0_p = Wk_p@bq_p ; y==3 w1c = Wqc@bkc ; y==4 c0c ----------------
template<int F32> __device__ void kbias_body(const void* W, const void* vec,
        float* out, float* vs) {
    int tid = threadIdx.x;
    for (int i = tid; i < D; i += 256) vs[i] = ld1<F32>(vec, i);
    __syncthreads();
    int row = blockIdx.x * 64 + (tid >> 2);
    int sub = tid & 3;
    float acc = 0.f;
    for (int i = 0; i < 48; ++i) {
        int k = i * 16 + sub * 4;
        float4 wv = ld4<F32>(W, (size_t)row * D + k);
        acc += wv.x * vs[k] + wv.y * vs[k + 1] + wv.z * vs[k + 2] + wv.w * vs[k + 3];
    }
    acc += __shfl_xor(acc, 1);
    acc += __shfl_xor(acc, 2);
    if (sub == 0) out[row] = acc;
}
template<int F32> __device__ void kc0_body(const void* bq, const void* bk,
        float* c0, float* red) {
    int tid = threadIdx.x;
    float s = 0.f;
    for (int i = tid; i < D; i += 256) s += ld1<F32>(bq, i) * ld1<F32>(bk, i);
    red[tid] = s; __syncthreads();
    for (int st = 128; st > 0; st >>= 1) { if (tid < st) red[tid] += red[tid + st]; __syncthreads(); }
    if (tid == 0) c0[0] = red[0];
}
__global__ __launch_bounds__(256) void kbias_row(PP pp, float* z0, float* w1,
        float* c0, const int* flag) {
    __shared__ float vs[D];
    __shared__ float red[256];
    int y = blockIdx.y;
    if (y == 4) {
        if (blockIdx.x != 0) return;
        if (flag[0]) kc0_body<1>(pp.b[2], pp.b[3], c0, red);
        else         kc0_body<0>(pp.b[2], pp.b[3], c0, red);
        return;
    }
    const void* W; const void* vec; float* out;
    if (y < 3) { W = pp.W[2 * y + 1]; vec = pp.b[2 * y]; out = z0 + y * D; }
    else       { W = pp.W[2];         vec = pp.b[3];     out = w1; }
    if (flag[0]) kbias_body<1>(W, vec, out, vs);
    else         kbias_body<0>(W, vec, out, vs);
}

// ---------------- kx: fused x->bf16 + 2 row-dots (Wa, w1c) ----------------
template<int F32> __device__ void kx_body(const void* x, const void* Wa,
        const void* ba, const float* w1, const float* c0, u16* xb, float* alog,
        float* tbuf, float* ws2) {
    int tid = threadIdx.x;
    for (int i = tid; i < D; i += 256) {
        ws2[i]     = ld1<F32>(Wa, i);
        ws2[D + i] = w1[i];
    }
    __syncthreads();
    int row = blockIdx.x * 32 + (tid >> 3);   // global row in [0, NB*L)
    int sub = tid & 7;
    float a0 = 0.f, a1 = 0.f;
    for (int i = 0; i < 24; ++i) {
        int k = i * 32 + sub * 4;
        float4 xv = ld4<F32>(x, (size_t)row * D + k);
        ushort4 o;
        o.x = f2b(xv.x); o.y = f2b(xv.y); o.z = f2b(xv.z); o.w = f2b(xv.w);
        *(ushort4*)(xb + (size_t)row * D + k) = o;
        a0 += xv.x * ws2[k] + xv.y * ws2[k + 1] + xv.z * ws2[k + 2] + xv.w * ws2[k + 3];
        a1 += xv.x * ws2[D + k] + xv.y * ws2[D + k + 1] + xv.z * ws2[D + k + 2] + xv.w * ws2[D + k + 3];
    }
    #pragma unroll
    for (int d = 1; d < 8; d <<= 1) {
        a0 += __shfl_xor(a0, d); a1 += __shfl_xor(a1, d);
    }
    int b = row >> 10, l = row & 1023;
    if (sub == 0) alog[row] = a0 + ld1<F32>(ba, 0);
    else if (sub == 1 && l < 512) tbuf[(size_t)b * 512 + l] = a1 + c0[0];
}
__global__ __launch_bounds__(256) void kx(const void* x, const void* Wa,
        const void* ba, const float* w1, const float* c0, u16* xb,
        float* alog, float* tbuf, const int* flag) {
    __shared__ float ws2[2 * D];
    if (flag[0]) kx_body<1>(x, Wa, ba, w1, c0, xb, alog, tbuf, ws2);
    else         kx_body<0>(x, Wa, ba, w1, c0, xb, alog, tbuf, ws2);
}

// ---------------- k0b: sep, gate softmax, zero accumulators ----------------
__global__ __launch_bounds__(256) void k0b(const int* __restrict__ ids,
        const int* __restrict__ padp, const float* __restrict__ alog,
        float* __restrict__ gate, int* __restrict__ sepArr,
        float* __restrict__ af, float* __restrict__ wrep, float* __restrict__ wsup,
        float* __restrict__ hacc, float* __restrict__ oacc,
        float* __restrict__ csup, float* __restrict__ crep,
        const int* __restrict__ flag) {
    __shared__ float red[256];
    __shared__ int sepSh;
    int is64 = flag[1];
    int b = blockIdx.x, tid = threadIdx.x;
    int pad = padp[0];
    int cnt = 0;
    for (int l = tid; l < L; l += 256) cnt += (ldid(ids, (size_t)b * L + l, is64) != pad) ? 1 : 0;
    red[tid] = (float)cnt; __syncthreads();
    for (int s = 128; s > 0; s >>= 1) { if (tid < s) red[tid] += red[tid + s]; __syncthreads(); }
    if (tid == 0) {
        int vl = (int)red[0];
        int sep = vl / 2; if (sep < 1) sep = 1; if (sep > L - 2) sep = L - 2;
        sepSh = sep; sepArr[b] = sep;
    }
    __syncthreads();
    int sep = sepSh;
    float lv[4]; int lidx[4];
    float mx = -3.4e38f;
    for (int u = 0; u < 4; ++u) {
        int l = tid + u * 256; lidx[u] = l;
        bool fm = (l < sep) && (ldid(ids, (size_t)b * L + l, is64) != pad);
        float v = fm ? alog[b * L + l] : NEGV;
        lv[u] = v; mx = fmaxf(mx, v);
    }
    red[tid] = mx; __syncthreads();
    for (int s = 128; s > 0; s >>= 1) { if (tid < s) red[tid] = fmaxf(red[tid], red[tid + s]); __syncthreads(); }
    mx = red[0]; __syncthreads();
    float se = 0.f;
    for (int u = 0; u < 4; ++u) { lv[u] = expf(lv[u] - mx); se += lv[u]; }
    red[tid] = se; __syncthreads();
    for (int s = 128; s > 0; s >>= 1) { if (tid < s) red[tid] += red[tid + s]; __syncthreads(); }
    float den = fmaxf(red[0], 1e-30f); __syncthreads();
    float gs = 0.f; float gv[4];
    for (int u = 0; u < 4; ++u) {
        int l = lidx[u];
        bool fm = (l < sep) && (ldid(ids, (size_t)b * L + l, is64) != pad);
        float p = lv[u] / den;
        gv[u] = fm ? p : 0.f;
        gs += gv[u];
    }
    red[tid] = gs; __syncthreads();
    for (int s = 128; s > 0; s >>= 1) { if (tid < s) red[tid] += red[tid + s]; __syncthreads(); }
    gs = red[0];
    float inv = 1.f / fmaxf(gs, 1e-8f);
    for (int u = 0; u < 4; ++u) gate[b * L + lidx[u]] = gv[u] * inv;
    for (int l = tid; l < L; l += 256) { csup[b * L + l] = 0.f; crep[b * L + l] = 0.f; }
    for (int i = tid; i < D; i += 256) {
        af[b * D + i] = 0.f; wrep[b * D + i] = 0.f; wsup[b * D + i] = 0.f;
        hacc[b * D + i] = 0.f; oacc[b * D + i] = 0.f;
    }
}

// ================= MFMA GEMM (A . B^T), async global->LDS staging =================
__device__ __forceinline__ void stage128_async(const u16* __restrict__ G, size_t ld,
        int r0, int k0, u16* S, int tid) {
    int rowa = tid >> 2, koa = (tid & 3) << 3;
    int wave = tid >> 6;
    const u16* g1 = &G[(size_t)(r0 + rowa) * ld + k0 + koa];
    const u16* g2 = &G[(size_t)(r0 + rowa + 64) * ld + k0 + koa];
    __builtin_amdgcn_global_load_lds((__attribute__((address_space(1))) void*)(u16*)g1,
        (__attribute__((address_space(3))) void*)(S + wave * 512), 16, 0, 0);
    __builtin_amdgcn_global_load_lds((__attribute__((address_space(1))) void*)(u16*)g2,
        (__attribute__((address_space(3))) void*)(S + 2048 + wave * 512), 16, 0, 0);
}
__device__ __forceinline__ void stage64_async(const u16* __restrict__ G, size_t ld,
        int r0, int k0, u16* S, int tid) {
    int rowa = tid >> 2, koa = (tid & 3) << 3;
    int wave = tid >> 6;
    const u16* g = &G[(size_t)(r0 + rowa) * ld + k0 + koa];
    __builtin_amdgcn_global_load_lds((__attribute__((address_space(1))) void*)(u16*)g,
        (__attribute__((address_space(3))) void*)(S + wave * 512), 16, 0, 0);
}

// As/Bs: 128*64 u16 each (two 128x32 panels; panel p at offset p*4096)
__device__ __forceinline__ void gemm_core128(const u16* __restrict__ A, size_t lda, int r0,
        const u16* __restrict__ B, size_t ldb, int c0, int K,
        u16* As, u16* Bs, float4v acc[4][4]) {
    int tid = threadIdx.x;
    int lane = tid & 63, wave = tid >> 6;
    int wm = (wave >> 1) << 6, wn = (wave & 1) << 6;
    int quad = lane >> 4, lrow = lane & 15;
    #pragma unroll
    for (int i = 0; i < 4; ++i)
        #pragma unroll
        for (int j = 0; j < 4; ++j) acc[i][j] = (float4v){0.f, 0.f, 0.f, 0.f};
    for (int k0 = 0; k0 < K; k0 += 64) {
        __syncthreads();
        stage128_async(A, lda, r0, k0, As, tid);
        stage128_async(A, lda, r0, k0 + 32, As + 4096, tid);
        stage128_async(B, ldb, c0, k0, Bs, tid);
        stage128_async(B, ldb, c0, k0 + 32, Bs + 4096, tid);
        __syncthreads();
        #pragma unroll
        for (int p = 0; p < 2; ++p) {
            const u16* Ap = As + p * 4096;
            const u16* Bp = Bs + p * 4096;
            short8 af[4], bf[4];
            #pragma unroll
            for (int i = 0; i < 4; ++i) af[i] = *(const short8*)&Ap[(wm + i * 16 + lrow) * 32 + quad * 8];
            #pragma unroll
            for (int j = 0; j < 4; ++j) bf[j] = *(const short8*)&Bp[(wn + j * 16 + lrow) * 32 + quad * 8];
            #pragma unroll
            for (int i = 0; i < 4; ++i)
                #pragma unroll
                for (int j = 0; j < 4; ++j)
                    acc[i][j] = MFMA_BF16(af[i], bf[j], acc[i][j], 0, 0, 0);
        }
    }
}

// gemm_core64: BM=64 variant. A 64 rows, B 128 cols.
// As: 64*64 u16 (panel p at +2048). Bs: 128*64 u16 (panel p at +4096).
__device__ __forceinline__ void gemm_core64(const u16* __restrict__ A, size_t lda, int r0,
        const u16* __restrict__ B, size_t ldb, int c0, int K,
        u16* As, u16* Bs, float4v acc[2][4]) {
    int tid = threadIdx.x;
    int lane = tid & 63, wave = tid >> 6;
    int wm = (wave >> 1) << 5, wn = (wave & 1) << 6;
    int quad = lane >> 4, lrow = lane & 15;
    #pragma unroll
    for (int i = 0; i < 2; ++i)
        #pragma unroll
        for (int j = 0; j < 4; ++j) acc[i][j] = (float4v){0.f, 0.f, 0.f, 0.f};
    for (int k0 = 0; k0 < K; k0 += 64) {
        __syncthreads();
        stage64_async(A, lda, r0, k0, As, tid);
        stage64_async(A, lda, r0, k0 + 32, As + 2048, tid);
        stage128_async(B, ldb, c0, k0, Bs, tid);
        stage128_async(B, ldb, c0, k0 + 32, Bs + 4096, tid);
        __syncthreads();
        #pragma unroll
        for (int p = 0; p < 2; ++p) {
            const u16* Ap = As + p * 2048;
            const u16* Bp = Bs + p * 4096;
            short8 fa[2], fb[4];
            #pragma unroll
            for (int i = 0; i < 2; ++i) fa[i] = *(const short8*)&Ap[(wm + i * 16 + lrow) * 32 + quad * 8];
            #pragma unroll
            for (int j = 0; j < 4; ++j) fb[j] = *(const short8*)&Bp[(wn + j * 16 + lrow) * 32 + quad * 8];
            #pragma unroll
            for (int i = 0; i < 2; ++i)
                #pragma unroll
                for (int j = 0; j < 4; ++j)
                    acc[i][j] = MFMA_BF16(fa[i], fb[j], acc[i][j], 0, 0, 0);
        }
    }
}

// ---------------- kM: Mt[j][k'] = sum_c Wk[j][c] Wq[k'][c], raw weights ----------------
// Register-staged (handles f32 or bf16 source), BK=32, R4-proven fragment layout.
template<int F32> __device__ __forceinline__ void stageW(const void* G, size_t ld,
        int r0, int k0, u16* S, int tid) {
    int row = tid >> 2, ko = (tid & 3) << 3;
    #pragma unroll
    for (int h = 0; h < 2; ++h) {
        size_t idx = (size_t)(r0 + row + h * 64) * ld + k0 + ko;
        uint4 o;
        if (F32) {
            float4 a = *(const float4*)((const float*)G + idx);
            float4 b = *(const float4*)((const float*)G + idx + 4);
            u16* po = (u16*)&o;
            po[0] = f2b(a.x); po[1] = f2b(a.y); po[2] = f2b(a.z); po[3] = f2b(a.w);
            po[4] = f2b(b.x); po[5] = f2b(b.y); po[6] = f2b(b.z); po[7] = f2b(b.w);
        } else {
            o = *(const uint4*)((const u16*)G + idx);
        }
        *(uint4*)&S[(size_t)(row + h * 64) * 32 + ko] = o;
    }
}
template<int F32> __device__ void kM_body(const void* Wk, const void* Wq,
        u16* out, u16* As, u16* Bs) {
    int r0 = blockIdx.y * 128, c0 = blockIdx.x * 128;
    int tid = threadIdx.x, lane = tid & 63, wave = tid >> 6;
    int wm = (wave >> 1) << 6, wn = (wave & 1) << 6;
    int quad = lane >> 4, lrow = lane & 15;
    float4v acc[4][4];
    #pragma unroll
    for (int i = 0; i < 4; ++i)
        #pragma unroll
        for (int j = 0; j < 4; ++j) acc[i][j] = (float4v){0.f, 0.f, 0.f, 0.f};
    for (int k0 = 0; k0 < D; k0 += 32) {
        __syncthreads();
        stageW<F32>(Wk, D, r0, k0, As, tid);
        stageW<F32>(Wq, D, c0, k0, Bs, tid);
        __syncthreads();
        short8 af[4], bf[4];
        #pragma unroll
        for (int i = 0; i < 4; ++i) af[i] = *(const short8*)&As[(wm + i * 16 + lrow) * 32 + quad * 8];
        #pragma unroll
        for (int j = 0; j < 4; ++j) bf[j] = *(const short8*)&Bs[(wn + j * 16 + lrow) * 32 + quad * 8];
        #pragma unroll
        for (int i = 0; i < 4; ++i)
            #pragma unroll
            for (int j = 0; j < 4; ++j)
                acc[i][j] = MFMA_BF16(af[i], bf[j], acc[i][j], 0, 0, 0);
    }
    #pragma unroll
    for (int i = 0; i < 4; ++i)
        #pragma unroll
        for (int j = 0; j < 4; ++j) {
            int brow = r0 + wm + i * 16 + quad * 4;
            int col = c0 + wn + j * 16 + lrow;
            #pragma unroll
            for (int r = 0; r < 4; ++r)
                out[(size_t)(brow + r) * D + col] = f2b(acc[i][j][r]);
        }
}
__global__ __launch_bounds__(256) void kM_mfma(PP pp, u16* __restrict__ Mt,
        const int* __restrict__ flag) {
    __shared__ __align__(16) u16 As[128 * 32];
    __shared__ __align__(16) u16 Bs[128 * 32];
    int p = blockIdx.z;
    u16* out = Mt + (size_t)p * D * D;
    if (flag[0]) kM_body<1>(pp.W[2 * p + 1], pp.W[2 * p], out, As, Bs);
    else         kM_body<0>(pp.W[2 * p + 1], pp.W[2 * p], out, As, Bs);
}

// kZ: Z[l][j] = sum_k xb[l][k] Mt[j][k] + z0[j]   (BM=64)
__global__ __launch_bounds__(256) void kZ_mfma(const u16* __restrict__ xb,
        const u16* __restrict__ Mt, const float* __restrict__ z0,
        u16* __restrict__ Zbuf, const int* __restrict__ sepArr) {
    __shared__ __align__(16) u16 As[64 * 64];
    __shared__ __align__(16) u16 Bs[128 * 64];
    int z = blockIdx.z;
    int p = z >> 3, b = z & 7;
    int sep = sepArr[b];
    int r0 = blockIdx.y * 64;
    if (r0 >= sep) return;
    int c0 = blockIdx.x * 128;
    float4v acc[2][4];
    gemm_core64(xb + (size_t)b * L * D, D, r0,
                Mt + (size_t)p * D * D, D, c0, D, As, Bs, acc);
    int lane = threadIdx.x & 63, wave = threadIdx.x >> 6;
    int wm = (wave >> 1) << 5, wn = (wave & 1) << 6;
    int quad = lane >> 4, lrow = lane & 15;
    const float* z0p = z0 + p * D;
    u16* out = Zbuf + ((size_t)p * NB + b) * 512 * D;
    #pragma unroll
    for (int i = 0; i < 2; ++i)
        #pragma unroll
        for (int j = 0; j < 4; ++j) {
            int brow = r0 + wm + i * 16 + quad * 4;
            int col = c0 + wn + j * 16 + lrow;
            float zb = z0p[col];
            #pragma unroll
            for (int r = 0; r < 4; ++r)
                out[(size_t)(brow + r) * D + col] = f2b(acc[i][j][r] + zb);
        }
}

// kS: merged score kernel, both paths BM=64.
// xi<8: sup path (A=Z0), xi>=8: cmb path (A=Zr,Zc). 32 KB LDS pool.
__global__ __launch_bounds__(256) void kS_mfma(const u16* __restrict__ Zbuf,
        const u16* __restrict__ xb, const float* __restrict__ tcbuf,
        const int* __restrict__ sepArr, u16* __restrict__ ssup,
        u16* __restrict__ scmb) {
    __shared__ __align__(16) u16 smem[16384];   // 32 KB: A0 (4096), A1 (4096), Bs (8192)
    int b = blockIdx.z;
    int sep = sepArr[b];
    int xi = blockIdx.x;
    int tid = threadIdx.x, lane = tid & 63, wave = tid >> 6;
    int quad = lane >> 4, lrow = lane & 15;
    int wm = (wave >> 1) << 5, wn = (wave & 1) << 6;
    int m0 = blockIdx.y * 128;
    if (m0 + 127 <= sep) return;
    u16* A0 = smem;
    u16* A1 = smem + 4096;
    u16* Bs = smem + 8192;
    const u16* X = xb + (size_t)b * L * D;
    if (xi < 8) {
        // ---- sup path ----
        int l0 = xi * 64;
        if (l0 >= sep) return;
        float4v acc[2][4];
        gemm_core64(Zbuf + (size_t)b * 512 * D, D, l0, X, D, m0, D, A0, Bs, acc);
        u16* out = ssup + (size_t)b * 512 * L;
        #pragma unroll
        for (int i = 0; i < 2; ++i)
            #pragma unroll
            for (int j = 0; j < 4; ++j) {
                int brow = l0 + wm + i * 16 + quad * 4;
                int col = m0 + wn + j * 16 + lrow;
                #pragma unroll
                for (int r = 0; r < 4; ++r)
                    out[(size_t)(brow + r) * L + col] = f2b(acc[i][j][r] * SCALE);
            }
        return;
    }
    // ---- cmb path ----
    int l0 = (xi - 8) * 64;
    if (l0 >= sep) return;
    const u16* Zr = Zbuf + ((size_t)2 * NB + b) * 512 * D;
    const u16* Zc = Zbuf + ((size_t)1 * NB + b) * 512 * D;
    float4v ar_[2][4], ac_[2][4];
    #pragma unroll
    for (int i = 0; i < 2; ++i)
        #pragma unroll
        for (int j = 0; j < 4; ++j) { ar_[i][j] = (float4v){0.f,0.f,0.f,0.f}; ac_[i][j] = (float4v){0.f,0.f,0.f,0.f}; }
    for (int k0 = 0; k0 < D; k0 += 64) {
        __syncthreads();
        stage64_async(Zr, D, l0, k0, A0, tid);
        stage64_async(Zr, D, l0, k0 + 32, A0 + 2048, tid);
        stage64_async(Zc, D, l0, k0, A1, tid);
        stage64_async(Zc, D, l0, k0 + 32, A1 + 2048, tid);
        stage128_async(X, D, m0, k0, Bs, tid);
        stage128_async(X, D, m0, k0 + 32, Bs + 4096, tid);
        __syncthreads();
        #pragma unroll
        for (int p = 0; p < 2; ++p) {
            const u16* Arp = A0 + p * 2048;
            const u16* Acp = A1 + p * 2048;
            const u16* Bp  = Bs + p * 4096;
            short8 fr[2], fc[2], fb[4];
            #pragma unroll
            for (int i = 0; i < 2; ++i) {
                fr[i] = *(const short8*)&Arp[(wm + i * 16 + lrow) * 32 + quad * 8];
                fc[i] = *(const short8*)&Acp[(wm + i * 16 + lrow) * 32 + quad * 8];
            }
            #pragma unroll
            for (int j = 0; j < 4; ++j) fb[j] = *(const short8*)&Bp[(wn + j * 16 + lrow) * 32 + quad * 8];
            #pragma unroll
            for (int i = 0; i < 2; ++i)
                #pragma unroll
                for (int j = 0; j < 4; ++j) {
                    ar_[i][j] = MFMA_BF16(fr[i], fb[j], ar_[i][j], 0, 0, 0);
                    ac_[i][j] = MFMA_BF16(fc[i], fb[j], ac_[i][j], 0, 0, 0);
                }
        }
    }
    const float* tc = tcbuf + (size_t)b * 512;
    u16* out = scmb + (size_t)b * 512 * L;
    #pragma unroll
    for (int i = 0; i < 2; ++i)
        #pragma unroll
        for (int j = 0; j < 4; ++j) {
            int brow = l0 + wm + i * 16 + quad * 4;
            int col = m0 + wn + j * 16 + lrow;
            #pragma unroll
            for (int r = 0; r < 4; ++r) {
                float vv = ar_[i][j][r] * SCALE
                         + tanhf((ac_[i][j][r] + tc[brow + r]) * SCALE);
                out[(size_t)(brow + r) * L + col] = f2b(vv);
            }
        }
}

// ---------------- k2bc: fused per-row softmax + column-weight accumulation ----------------
__global__ __launch_bounds__(256) void k2bc(const u16* __restrict__ ssup,
        const u16* __restrict__ scmb, const int* __restrict__ ids,
        const int* __restrict__ padp, const int* __restrict__ sepArr,
        const float* __restrict__ gate, float* __restrict__ csup,
        float* __restrict__ crep, const int* __restrict__ flag) {
    __shared__ float colacc[4][2][1024];   // [wave][mat][col] = 32 KB
    int b = blockIdx.y;
    int sep = sepArr[b];
    int l0 = blockIdx.x * 8;
    int tid = threadIdx.x, lane = tid & 63, w = tid >> 6;
    for (int i = tid; i < 4 * 2 * 1024; i += 256) ((float*)colacc)[i] = 0.f;
    __syncthreads();
    if (l0 < sep) {
        int is64 = flag[1];
        int pad = padp[0];
        unsigned int okmask = 0;
        #pragma unroll
        for (int u = 0; u < 16; ++u) {
            int m = u * 64 + lane;
            bool ok = (m > sep) && (ldid(ids, (size_t)b * L + m, is64) != pad);
            okmask |= (ok ? 1u : 0u) << u;
        }
        for (int t = 0; t < 2; ++t) {
            int l = l0 + w * 2 + t;
            if (l >= sep) continue;
            float g = gate[b * L + l];
            if (g == 0.f) continue;
            const u16* rs = ssup + ((size_t)b * 512 + l) * L;
            const u16* rc = scmb + ((size_t)b * 512 + l) * L;
            float s0[16], s1[16];
            float mx0 = -3.4e38f, mx1 = -3.4e38f;
            #pragma unroll
            for (int u = 0; u < 16; ++u) {
                int m = u * 64 + lane;
                bool ok = (okmask >> u) & 1u;
                s0[u] = ok ? b2f(rs[m]) : NEGV;
                s1[u] = ok ? b2f(rc[m]) : NEGV;
                mx0 = fmaxf(mx0, s0[u]); mx1 = fmaxf(mx1, s1[u]);
            }
            #pragma unroll
            for (int d = 1; d < 64; d <<= 1) {
                mx0 = fmaxf(mx0, __shfl_xor(mx0, d));
                mx1 = fmaxf(mx1, __shfl_xor(mx1, d));
            }
            float e0 = 0.f, e1 = 0.f;
            #pragma unroll
            for (int u = 0; u < 16; ++u) {
                s0[u] = expf(s0[u] - mx0); e0 += s0[u];
                s1[u] = expf(s1[u] - mx1); e1 += s1[u];
            }
            #pragma unroll
            for (int d = 1; d < 64; d <<= 1) {
                e0 += __shfl_xor(e0, d);
                e1 += __shfl_xor(e1, d);
            }
            float i0 = g / fmaxf(e0, 1e-30f), i1 = g / fmaxf(e1, 1e-30f);
            #pragma unroll
            for (int u = 0; u < 16; ++u) {
                int m = u * 64 + lane;
                colacc[w][0][m] += s0[u] * i0;
                colacc[w][1][m] += s1[u] * i1;
            }
        }
    }
    __syncthreads();
    for (int m = tid; m < 1024; m += 256) {
        float a0 = colacc[0][0][m] + colacc[1][0][m] + colacc[2][0][m] + colacc[3][0][m];
        float a1 = colacc[0][1][m] + colacc[1][1][m] + colacc[2][1][m] + colacc[3][1][m];
        if (a0 != 0.f) atomicAdd(&csup[b * L + m], a0);
        if (a1 != 0.f) atomicAdd(&crep[b * L + m], a1);
    }
}

// ---------------- K3: af/w_rep/w_sup weighted sums over xb (bf16) ----------------
__global__ __launch_bounds__(256) void k3(const u16* __restrict__ xb,
        const float* __restrict__ gate, const float* __restrict__ csup,
        const float* __restrict__ crep, float* __restrict__ af,
        float* __restrict__ wrep, float* __restrict__ wsup) {
    int b = blockIdx.y, c = blockIdx.x;
    int tid = threadIdx.x;
    float a0 = 0.f, a1 = 0.f, a2 = 0.f;
    float r0 = 0.f, r1 = 0.f, r2 = 0.f;
    float q0 = 0.f, q1 = 0.f, q2 = 0.f;
    for (int mm = 0; mm < 16; ++mm) {
        int m = c * 16 + mm;
        float wg = gate[b * L + m], wr = crep[b * L + m], wq = csup[b * L + m];
        if (wg == 0.f && wr == 0.f && wq == 0.f) continue;
        size_t base = ((size_t)b * L + m) * D;
        float x0 = b2f(xb[base + tid]);
        float x1 = b2f(xb[base + tid + 256]);
        float x2 = b2f(xb[base + tid + 512]);
        a0 += wg * x0; a1 += wg * x1; a2 += wg * x2;
        r0 += wr * x0; r1 += wr * x1; r2 += wr * x2;
        q0 += wq * x0; q1 += wq * x1; q2 += wq * x2;
    }
    atomicAdd(&af[b * D + tid], a0); atomicAdd(&af[b * D + tid + 256], a1); atomicAdd(&af[b * D + tid + 512], a2);
    atomicAdd(&wrep[b * D + tid], r0); atomicAdd(&wrep[b * D + tid + 256], r1); atomicAdd(&wrep[b * D + tid + 512], r2);
    atomicAdd(&wsup[b * D + tid], q0); atomicAdd(&wsup[b * D + tid + 256], q1); atomicAdd(&wsup[b * D + tid + 512], q2);
}

// ---------------- kh1: hacc += fused @ Wf1 (split-K) ----------------
template<int F32> __device__ void kh1_body(const float* af, const float* wrep,
        const float* wsup, const void* Wf1, float* hacc, float* fs) {
    int tid = threadIdx.x;
    int c0 = blockIdx.x * 128, k0 = blockIdx.y * 144;
    for (int e = tid; e < 8 * 144; e += 256) {
        int b = e / 144, kk = e - b * 144;
        int k = k0 + kk;
        float v = (k < D) ? af[b * D + k] : (k < 2 * D) ? wrep[b * D + k - D]
                                                        : wsup[b * D + k - 2 * D];
        fs[b * 144 + kk] = v;
    }
    __syncthreads();
    int col = c0 + (tid & 127);
    int kg = tid >> 7;
    float acc[NB];
    #pragma unroll
    for (int b = 0; b < NB; ++b) acc[b] = 0.f;
    #pragma unroll 4
    for (int r = 0; r < 72; ++r) {
        int kk = kg * 72 + r;
        float w = ld1<F32>(Wf1, (size_t)(k0 + kk) * D + col);
        #pragma unroll
        for (int b = 0; b < NB; ++b) acc[b] += fs[b * 144 + kk] * w;
    }
    #pragma unroll
    for (int b = 0; b < NB; ++b) atomicAdd(&hacc[b * D + col], acc[b]);
}
__global__ __launch_bounds__(256) void kh1(const float* af, const float* wrep,
        const float* wsup, const void* Wf1, float* hacc, const int* flag) {
    __shared__ float fs[8 * 144];
    if (flag[0]) kh1_body<1>(af, wrep, wsup, Wf1, hacc, fs);
    else         kh1_body<0>(af, wrep, wsup, Wf1, hacc, fs);
}

// ---------------- kh2: oacc += relu(hacc+bf1) @ Wf2 (split-K) ----------------
template<int F32> __device__ void kh2_body(const float* hacc, const void* bf1,
        const void* Wf2, float* oacc, float* hsl) {
    int tid = threadIdx.x;
    int c0 = blockIdx.x * 128, k0 = blockIdx.y * 96;
    for (int e = tid; e < 8 * 96; e += 256) {
        int b = e / 96, kk = e - b * 96;
        int k = k0 + kk;
        hsl[b * 96 + kk] = fmaxf(hacc[b * D + k] + ld1<F32>(bf1, k), 0.f);
    }
    __syncthreads();
    int col = c0 + (tid & 127);
    int kg = tid >> 7;
    float acc[NB];
    #pragma unroll
    for (int b = 0; b < NB; ++b) acc[b] = 0.f;
    #pragma unroll 4
    for (int r = 0; r < 48; ++r) {
        int kk = kg * 48 + r;
        float w = ld1<F32>(Wf2, (size_t)(k0 + kk) * D + col);
        #pragma unroll
        for (int b = 0; b < NB; ++b) acc[b] += hsl[b * 96 + kk] * w;
    }
    #pragma unroll
    for (int b = 0; b < NB; ++b) atomicAdd(&oacc[b * D + col], acc[b]);
}
__global__ __launch_bounds__(256) void kh2(const float* hacc, const void* bf1,
        const void* Wf2, float* oacc, const int* flag) {
    __shared__ float hsl[8 * 96];
    if (flag[0]) kh2_body<1>(hacc, bf1, Wf2, oacc, hsl);
    else         kh2_body<0>(hacc, bf1, Wf2, oacc, hsl);
}

// ---------------- kln: out = LN(oacc + bf2) * gamma + beta ----------------
template<int F32> __device__ void kln_body(const float* oacc, const void* bf2,
        const void* gamma, const void* beta, void* out, float* red) {
    int b = blockIdx.x, tid = threadIdx.x;
    float o[3];
    #pragma unroll
    for (int u = 0; u < 3; ++u) {
        int i = tid + u * 256;
        o[u] = oacc[b * D + i] + ld1<F32>(bf2, i);
    }
    red[tid] = o[0] + o[1] + o[2]; __syncthreads();
    for (int s = 128; s > 0; s >>= 1) { if (tid < s) red[tid] += red[tid + s]; __syncthreads(); }
    float mu = red[0] / (float)D; __syncthreads();
    float vs = 0.f;
    #pragma unroll
    for (int u = 0; u < 3; ++u) vs += (o[u] - mu) * (o[u] - mu);
    red[tid] = vs; __syncthreads();
    for (int s = 128; s > 0; s >>= 1) { if (tid < s) red[tid] += red[tid + s]; __syncthreads(); }
    float var = red[0] / (float)D;
    float rstd = 1.0f / sqrtf(var + 1e-5f);
    #pragma unroll
    for (int u = 0; u < 3; ++u) {
        int i = tid + u * 256;
        float v = (o[u] - mu) * rstd * ld1<F32>(gamma, i) + ld1<F32>(beta, i);
        if (F32) ((float*)out)[b * D + i] = v;
        else     ((u16*)out)[b * D + i] = f2b(v);
    }
}
__global__ __launch_bounds__(256) void kln(const float* oacc, const void* bf2,
        const void* gamma, const void* beta, void* out, const int* flag) {
    __shared__ float red[256];
    if (flag[0]) kln_body<1>(oacc, bf2, gamma, beta, out, red);
    else         kln_body<0>(oacc, bf2, gamma, beta, out, red);
}

extern "C" void kernel_launch(void* const* d_in, const int* in_sizes, int n_in,
                              void* d_out, int out_size, void* d_ws, size_t ws_size,
                              hipStream_t stream) {
    const void* x    = d_in[0];
    const int* ids   = (const int*)d_in[1];
    const int* padp  = (const int*)d_in[2];
    const void* Wa   = d_in[3];
    const void* ba   = d_in[4];
    PP pp;
    pp.W[0] = d_in[5];  pp.b[0] = d_in[6];    // qs
    pp.W[1] = d_in[7];  pp.b[1] = d_in[8];    // ks
    pp.W[2] = d_in[9];  pp.b[2] = d_in[10];   // qc
    pp.W[3] = d_in[11]; pp.b[3] = d_in[12];   // kc
    pp.W[4] = d_in[13]; pp.b[4] = d_in[14];   // qr
    pp.W[5] = d_in[15]; pp.b[5] = d_in[16];   // kr
    const void* Wf1 = d_in[17]; const void* bf1 = d_in[18];
    const void* Wf2 = d_in[19]; const void* bf2 = d_in[20];
    const void* gamma = d_in[21]; const void* beta = d_in[22];

    char* ws = (char*)d_ws;
    int*   flag   = (int*)(ws + WS_FLAG);
    int*   sepArr = (int*)(ws + WS_SEP);
    float* c0   = (float*)(ws + WS_C0);
    float* z0   = (float*)(ws + WS_Z0);
    float* w1   = (float*)(ws + WS_W1);
    float* gate = (float*)(ws + WS_GATE);
    float* csup = (float*)(ws + WS_CSUP);
    float* crep = (float*)(ws + WS_CREP);
    float* af   = (float*)(ws + WS_AF);
    float* wrep = (float*)(ws + WS_WREP);
    float* wsup = (float*)(ws + WS_WSUP);
    float* hacc = (float*)(ws + WS_HACC);
    float* oacc = (float*)(ws + WS_OACC);
    float* alog = (float*)(ws + WS_ALOG);
    float* tbuf = (float*)(ws + WS_T);
    u16* xb   = (u16*)(ws + WS_XB);
    u16* Zbuf = (u16*)(ws + WS_Z);
    u16* Mt   = (u16*)(ws + WS_M);
    u16* ssup = (u16*)(ws + WS_SSUP);
    u16* scmb = (u16*)(ws + WS_SCMB);

    kdetect<<<dim3(1), dim3(128), 0, stream>>>(x, ids, flag);
    kbias_row<<<dim3(12, 5), dim3(256), 0, stream>>>(pp, z0, w1, c0, flag);
    kx<<<dim3(256), dim3(256), 0, stream>>>(x, Wa, ba, w1, c0, xb, alog, tbuf, flag);
    k0b<<<dim3(NB), dim3(256), 0, stream>>>(ids, padp, alog, gate, sepArr,
                                            af, wrep, wsup, hacc, oacc, csup, crep, flag);
    kM_mfma<<<dim3(6, 6, 3), dim3(256), 0, stream>>>(pp, Mt, flag);
    kZ_mfma<<<dim3(6, 8, 24), dim3(256), 0, stream>>>(xb, Mt, z0, Zbuf, sepArr);
    kS_mfma<<<dim3(16, 8, NB), dim3(256), 0, stream>>>(Zbuf, xb, tbuf, sepArr, ssup, scmb);
    k2bc<<<dim3(64, NB), dim3(256), 0, stream>>>(ssup, scmb, ids, padp, sepArr,
                                                 gate, csup, crep, flag);
    k3<<<dim3(64, NB), dim3(256), 0, stream>>>(xb, gate, csup, crep, af, wrep, wsup);
    kh1<<<dim3(6, 16), dim3(256), 0, stream>>>(af, wrep, wsup, Wf1, hacc, flag);
    kh2<<<dim3(6, 8), dim3(256), 0, stream>>>(hacc, bf1, Wf2, oacc, flag);
    kln<<<dim3(NB), dim3(256), 0, stream>>>(oacc, bf2, gamma, beta, d_out, flag);
}

// Round 13
// 284.539 us; speedup vs baseline: 1.0391x; 1.0391x over previous
//
#include <hip/hip_runtime.h>
#include <math.h>

#define L 1024
#define NB 8
#define D 768
#define NEGV (-9.0e15f)
#define SCALE 0.036084391824351615f  // 1/sqrt(768)

typedef unsigned short u16;
typedef __attribute__((ext_vector_type(8))) short short8;
typedef __attribute__((ext_vector_type(4))) float float4v;
#define MFMA_BF16 __builtin_amdgcn_mfma_f32_16x16x32_bf16

__device__ __forceinline__ float b2f(u16 u) {
    union { unsigned int i; float f; } v; v.i = ((unsigned int)u) << 16; return v.f;
}
__device__ __forceinline__ u16 f2b(float f) {
    union { float fv; unsigned int i; } v; v.fv = f;
    unsigned int x = v.i;
    x += 0x7fffu + ((x >> 16) & 1u);   // RNE
    return (u16)(x >> 16);
}

template<int F32>
__device__ __forceinline__ float4 ld4(const void* p, size_t idx) {
    if (F32) return *(const float4*)((const float*)p + idx);
    ushort4 v = *(const ushort4*)((const u16*)p + idx);
    return make_float4(b2f(v.x), b2f(v.y), b2f(v.z), b2f(v.w));
}
template<int F32>
__device__ __forceinline__ float ld1(const void* p, size_t idx) {
    if (F32) return ((const float*)p)[idx];
    return b2f(((const u16*)p)[idx]);
}
__device__ __forceinline__ int ldid(const int* p, size_t idx, int is64) {
    return is64 ? p[idx * 2] : p[idx];
}

// ---------------- workspace layout (bytes) ----------------
#define WS_FLAG  ((size_t)0)
#define WS_SEP   ((size_t)64)
#define WS_C0    ((size_t)128)        // 1 f32 (con)
#define WS_Z0    ((size_t)192)        // 3*D f32
#define WS_W1    ((size_t)9472)       // D f32 (con only)
#define WS_GATE  ((size_t)18752)
#define WS_CSUP  ((size_t)51520)
#define WS_CREP  ((size_t)84288)
#define WS_AF    ((size_t)117056)
#define WS_WREP  ((size_t)141632)
#define WS_WSUP  ((size_t)166208)
#define WS_HACC  ((size_t)190784)
#define WS_ALOG  ((size_t)215360)
#define WS_T     ((size_t)248128)     // NB*512 f32 (con t only)
#define WS_OACC  ((size_t)303104)
#define WS_XB    ((size_t)524288)     // NB*L*D bf16 -> 13107200
#define WS_Z     ((size_t)13107200)   // 3*NB*512*D bf16 -> 31981568
#define WS_SSUP  ((size_t)31981568)   // NB*512*L bf16 -> 40370176
#define WS_WB    WS_SSUP              // 6*D*D bf16 (dead before kS writes)
#define WS_SCMB  ((size_t)40370176)   // NB*512*L bf16 -> 48758784
#define WS_M     WS_SCMB              // 3*D*D bf16 (dead before kS writes)

struct PP { const void* W[6]; const void* b[6]; };

// ---------------- detect dtypes (standalone, proven) ----------------
__global__ __launch_bounds__(128) void kdetect(const void* x, const void* ids, int* flag) {
    __shared__ int cnt[2];
    int tid = threadIdx.x;
    if (tid == 0) { cnt[0] = 0; cnt[1] = 0; }
    __syncthreads();
    if (tid < 64) {
        u16 u = ((const u16*)x)[tid * 2];
        int e = (u >> 7) & 0xFF;
        if (e >= 100 && e <= 140) atomicAdd(&cnt[0], 1);
    } else {
        int v = ((const int*)ids)[(tid - 64) * 2 + 1];
        if (v != 0) atomicAdd(&cnt[1], 1);
    }
    __syncthreads();
    if (tid == 0) {
        flag[0] = (cnt[0] < 32) ? 1 : 0;   // 1 => floats are f32
        flag[1] = (cnt[1] == 0) ? 1 : 0;   // 1 => ids are int64
    }
}

// ---------------- kbias_row: y<3 z0_p = Wk_p@bq_p ; y==3 w1c = Wqc@bkc ; y==4 c0c ----------------
template<int F32> __device__ void kbias_body(const void* W, const void* vec,
        float* out, float* vs) {
    int tid = threadIdx.x;
    for (int i = tid; i < D; i += 256) vs[i] = ld1<F32>(vec, i);
    __syncthreads();
    int row = blockIdx.x * 64 + (tid >> 2);
    int sub = tid & 3;
    float acc = 0.f;
    for (int i = 0; i < 48; ++i) {
        int k = i * 16 + sub * 4;
        float4 wv = ld4<F32>(W, (size_t)row * D + k);
        acc += wv.x * vs[k] + wv.y * vs[k + 1] + wv.z * vs[k + 2] + wv.w * vs[k + 3];
    }
    acc += __shfl_xor(acc, 1);
    acc += __shfl_xor(acc, 2);
    if (sub == 0) out[row] = acc;
}
template<int F32> __device__ void kc0_body(const void* bq, const void* bk,
        float* c0, float* red) {
    int tid = threadIdx.x;
    float s = 0.f;
    for (int i = tid; i < D; i += 256) s += ld1<F32>(bq, i) * ld1<F32>(bk, i);
    red[tid] = s; __syncthreads();
    for (int st = 128; st > 0; st >>= 1) { if (tid < st) red[tid] += red[tid + st]; __syncthreads(); }
    if (tid == 0) c0[0] = red[0];
}
__global__ __launch_bounds__(256) void kbias_row(PP pp, float* z0, float* w1,
        float* c0, const int* flag) {
    __shared__ float vs[D];
    __shared__ float red[256];
    int y = blockIdx.y;
    if (y == 4) {
        if (blockIdx.x != 0) return;
        if (flag[0]) kc0_body<1>(pp.b[2], pp.b[3], c0, red);
        else         kc0_body<0>(pp.b[2], pp.b[3], c0, red);
        return;
    }
    const void* W; const void* vec; float* out;
    if (y < 3) { W = pp.W[2 * y + 1]; vec = pp.b[2 * y]; out = z0 + y * D; }
    else       { W = pp.W[2];         vec = pp.b[3];     out = w1; }
    if (flag[0]) kbias_body<1>(W, vec, out, vs);
    else         kbias_body<0>(W, vec, out, vs);
}

// ---------------- kx: fused x->bf16 + 2 row-dots (Wa, w1c) + W->bf16 ----------------
template<int F32> __device__ void kx_body(const void* x, const void* Wa,
        const void* ba, const float* w1, const float* c0, u16* xb, float* alog,
        float* tbuf, float* ws2) {
    int tid = threadIdx.x;
    for (int i = tid; i < D; i += 256) {
        ws2[i]     = ld1<F32>(Wa, i);
        ws2[D + i] = w1[i];
    }
    __syncthreads();
    int row = blockIdx.x * 32 + (tid >> 3);   // global row in [0, NB*L)
    int sub = tid & 7;
    float a0 = 0.f, a1 = 0.f;
    for (int i = 0; i < 24; ++i) {
        int k = i * 32 + sub * 4;
        float4 xv = ld4<F32>(x, (size_t)row * D + k);
        ushort4 o;
        o.x = f2b(xv.x); o.y = f2b(xv.y); o.z = f2b(xv.z); o.w = f2b(xv.w);
        *(ushort4*)(xb + (size_t)row * D + k) = o;
        a0 += xv.x * ws2[k] + xv.y * ws2[k + 1] + xv.z * ws2[k + 2] + xv.w * ws2[k + 3];
        a1 += xv.x * ws2[D + k] + xv.y * ws2[D + k + 1] + xv.z * ws2[D + k + 2] + xv.w * ws2[D + k + 3];
    }
    #pragma unroll
    for (int d = 1; d < 8; d <<= 1) {
        a0 += __shfl_xor(a0, d); a1 += __shfl_xor(a1, d);
    }
    int b = row >> 10, l = row & 1023;
    if (sub == 0) alog[row] = a0 + ld1<F32>(ba, 0);
    else if (sub == 1 && l < 512) tbuf[(size_t)b * 512 + l] = a1 + c0[0];
}
__global__ __launch_bounds__(256) void kx(const void* x, PP pp, const void* Wa,
        const void* ba, const float* w1, const float* c0, u16* xb, u16* Wb,
        float* alog, float* tbuf, const int* flag) {
    __shared__ float ws2[2 * D];
    int bid = blockIdx.x;
    if (bid < 256) {
        if (flag[0]) kx_body<1>(x, Wa, ba, w1, c0, xb, alog, tbuf, ws2);
        else         kx_body<0>(x, Wa, ba, w1, c0, xb, alog, tbuf, ws2);
        return;
    }
    int t = (bid - 256) / 288, inner = (bid - 256) % 288;
    const void* src = pp.W[t];
    u16* dst = Wb + (size_t)t * D * D;
    size_t base = ((size_t)inner * 256 + threadIdx.x) * 8;
    if (flag[0]) {
        float4 a = *(const float4*)((const float*)src + base);
        float4 b = *(const float4*)((const float*)src + base + 4);
        uint4 o; u16* po = (u16*)&o;
        po[0] = f2b(a.x); po[1] = f2b(a.y); po[2] = f2b(a.z); po[3] = f2b(a.w);
        po[4] = f2b(b.x); po[5] = f2b(b.y); po[6] = f2b(b.z); po[7] = f2b(b.w);
        *(uint4*)(dst + base) = o;
    } else {
        *(uint4*)(dst + base) = *(const uint4*)((const u16*)src + base);
    }
}

// ---------------- k0b: sep, gate softmax, zero accumulators ----------------
__global__ __launch_bounds__(256) void k0b(const int* __restrict__ ids,
        const int* __restrict__ padp, const float* __restrict__ alog,
        float* __restrict__ gate, int* __restrict__ sepArr,
        float* __restrict__ af, float* __restrict__ wrep, float* __restrict__ wsup,
        float* __restrict__ hacc, float* __restrict__ oacc,
        float* __restrict__ csup, float* __restrict__ crep,
        const int* __restrict__ flag) {
    __shared__ float red[256];
    __shared__ int sepSh;
    int is64 = flag[1];
    int b = blockIdx.x, tid = threadIdx.x;
    int pad = padp[0];
    int cnt = 0;
    for (int l = tid; l < L; l += 256) cnt += (ldid(ids, (size_t)b * L + l, is64) != pad) ? 1 : 0;
    red[tid] = (float)cnt; __syncthreads();
    for (int s = 128; s > 0; s >>= 1) { if (tid < s) red[tid] += red[tid + s]; __syncthreads(); }
    if (tid == 0) {
        int vl = (int)red[0];
        int sep = vl / 2; if (sep < 1) sep = 1; if (sep > L - 2) sep = L - 2;
        sepSh = sep; sepArr[b] = sep;
    }
    __syncthreads();
    int sep = sepSh;
    float lv[4]; int lidx[4];
    float mx = -3.4e38f;
    for (int u = 0; u < 4; ++u) {
        int l = tid + u * 256; lidx[u] = l;
        bool fm = (l < sep) && (ldid(ids, (size_t)b * L + l, is64) != pad);
        float v = fm ? alog[b * L + l] : NEGV;
        lv[u] = v; mx = fmaxf(mx, v);
    }
    red[tid] = mx; __syncthreads();
    for (int s = 128; s > 0; s >>= 1) { if (tid < s) red[tid] = fmaxf(red[tid], red[tid + s]); __syncthreads(); }
    mx = red[0]; __syncthreads();
    float se = 0.f;
    for (int u = 0; u < 4; ++u) { lv[u] = expf(lv[u] - mx); se += lv[u]; }
    red[tid] = se; __syncthreads();
    for (int s = 128; s > 0; s >>= 1) { if (tid < s) red[tid] += red[tid + s]; __syncthreads(); }
    float den = fmaxf(red[0], 1e-30f); __syncthreads();
    float gs = 0.f; float gv[4];
    for (int u = 0; u < 4; ++u) {
        int l = lidx[u];
        bool fm = (l < sep) && (ldid(ids, (size_t)b * L + l, is64) != pad);
        float p = lv[u] / den;
        gv[u] = fm ? p : 0.f;
        gs += gv[u];
    }
    red[tid] = gs; __syncthreads();
    for (int s = 128; s > 0; s >>= 1) { if (tid < s) red[tid] += red[tid + s]; __syncthreads(); }
    gs = red[0];
    float inv = 1.f / fmaxf(gs, 1e-8f);
    for (int u = 0; u < 4; ++u) gate[b * L + lidx[u]] = gv[u] * inv;
    for (int l = tid; l < L; l += 256) { csup[b * L + l] = 0.f; crep[b * L + l] = 0.f; }
    for (int i = tid; i < D; i += 256) {
        af[b * D + i] = 0.f; wrep[b * D + i] = 0.f; wsup[b * D + i] = 0.f;
        hacc[b * D + i] = 0.f; oacc[b * D + i] = 0.f;
    }
}

// ================= MFMA GEMM (A . B^T), async global->LDS staging =================
// BK=64: two 32-K panels staged per barrier.
__device__ __forceinline__ void stage128_async(const u16* __restrict__ G, size_t ld,
        int r0, int k0, u16* S, int tid) {
    int rowa = tid >> 2, koa = (tid & 3) << 3;
    int wave = tid >> 6;
    const u16* g1 = &G[(size_t)(r0 + rowa) * ld + k0 + koa];
    const u16* g2 = &G[(size_t)(r0 + rowa + 64) * ld + k0 + koa];
    __builtin_amdgcn_global_load_lds((__attribute__((address_space(1))) void*)(u16*)g1,
        (__attribute__((address_space(3))) void*)(S + wave * 512), 16, 0, 0);
    __builtin_amdgcn_global_load_lds((__attribute__((address_space(1))) void*)(u16*)g2,
        (__attribute__((address_space(3))) void*)(S + 2048 + wave * 512), 16, 0, 0);
}
__device__ __forceinline__ void stage64_async(const u16* __restrict__ G, size_t ld,
        int r0, int k0, u16* S, int tid) {
    int rowa = tid >> 2, koa = (tid & 3) << 3;
    int wave = tid >> 6;
    const u16* g = &G[(size_t)(r0 + rowa) * ld + k0 + koa];
    __builtin_amdgcn_global_load_lds((__attribute__((address_space(1))) void*)(u16*)g,
        (__attribute__((address_space(3))) void*)(S + wave * 512), 16, 0, 0);
}

// As/Bs: 128*64 u16 each (two 128x32 panels; panel p at offset p*4096)
__device__ __forceinline__ void gemm_core128(const u16* __restrict__ A, size_t lda, int r0,
        const u16* __restrict__ B, size_t ldb, int c0, int K,
        u16* As, u16* Bs, float4v acc[4][4]) {
    int tid = threadIdx.x;
    int lane = tid & 63, wave = tid >> 6;
    int wm = (wave >> 1) << 6, wn = (wave & 1) << 6;
    int quad = lane >> 4, lrow = lane & 15;
    #pragma unroll
    for (int i = 0; i < 4; ++i)
        #pragma unroll
        for (int j = 0; j < 4; ++j) acc[i][j] = (float4v){0.f, 0.f, 0.f, 0.f};
    for (int k0 = 0; k0 < K; k0 += 64) {
        __syncthreads();
        stage128_async(A, lda, r0, k0, As, tid);
        stage128_async(A, lda, r0, k0 + 32, As + 4096, tid);
        stage128_async(B, ldb, c0, k0, Bs, tid);
        stage128_async(B, ldb, c0, k0 + 32, Bs + 4096, tid);
        __syncthreads();
        #pragma unroll
        for (int p = 0; p < 2; ++p) {
            const u16* Ap = As + p * 4096;
            const u16* Bp = Bs + p * 4096;
            short8 af[4], bf[4];
            #pragma unroll
            for (int i = 0; i < 4; ++i) af[i] = *(const short8*)&Ap[(wm + i * 16 + lrow) * 32 + quad * 8];
            #pragma unroll
            for (int j = 0; j < 4; ++j) bf[j] = *(const short8*)&Bp[(wn + j * 16 + lrow) * 32 + quad * 8];
            #pragma unroll
            for (int i = 0; i < 4; ++i)
                #pragma unroll
                for (int j = 0; j < 4; ++j)
                    acc[i][j] = MFMA_BF16(af[i], bf[j], acc[i][j], 0, 0, 0);
        }
    }
}

// gemm_core64: BM=64 variant. A 64 rows, B 128 cols.
// As: 64*64 u16 (panel p at +2048). Bs: 128*64 u16 (panel p at +4096).
__device__ __forceinline__ void gemm_core64(const u16* __restrict__ A, size_t lda, int r0,
        const u16* __restrict__ B, size_t ldb, int c0, int K,
        u16* As, u16* Bs, float4v acc[2][4]) {
    int tid = threadIdx.x;
    int lane = tid & 63, wave = tid >> 6;
    int wm = (wave >> 1) << 5, wn = (wave & 1) << 6;
    int quad = lane >> 4, lrow = lane & 15;
    #pragma unroll
    for (int i = 0; i < 2; ++i)
        #pragma unroll
        for (int j = 0; j < 4; ++j) acc[i][j] = (float4v){0.f, 0.f, 0.f, 0.f};
    for (int k0 = 0; k0 < K; k0 += 64) {
        __syncthreads();
        stage64_async(A, lda, r0, k0, As, tid);
        stage64_async(A, lda, r0, k0 + 32, As + 2048, tid);
        stage128_async(B, ldb, c0, k0, Bs, tid);
        stage128_async(B, ldb, c0, k0 + 32, Bs + 4096, tid);
        __syncthreads();
        #pragma unroll
        for (int p = 0; p < 2; ++p) {
            const u16* Ap = As + p * 2048;
            const u16* Bp = Bs + p * 4096;
            short8 fa[2], fb[4];
            #pragma unroll
            for (int i = 0; i < 2; ++i) fa[i] = *(const short8*)&Ap[(wm + i * 16 + lrow) * 32 + quad * 8];
            #pragma unroll
            for (int j = 0; j < 4; ++j) fb[j] = *(const short8*)&Bp[(wn + j * 16 + lrow) * 32 + quad * 8];
            #pragma unroll
            for (int i = 0; i < 2; ++i)
                #pragma unroll
                for (int j = 0; j < 4; ++j)
                    acc[i][j] = MFMA_BF16(fa[i], fb[j], acc[i][j], 0, 0, 0);
        }
    }
}

// kM: Mt[j][k'] = sum_c Wk[j][c] Wq[k'][c]
__global__ __launch_bounds__(256) void kM_mfma(const u16* __restrict__ Wb, u16* __restrict__ Mt) {
    __shared__ __align__(16) u16 As[128 * 64];
    __shared__ __align__(16) u16 Bs[128 * 64];
    int p = blockIdx.z;
    int r0 = blockIdx.y * 128, c0 = blockIdx.x * 128;
    float4v acc[4][4];
    gemm_core128(Wb + (size_t)(2 * p + 1) * D * D, D, r0,
                 Wb + (size_t)(2 * p) * D * D, D, c0, D, As, Bs, acc);
    int lane = threadIdx.x & 63, wave = threadIdx.x >> 6;
    int wm = (wave >> 1) << 6, wn = (wave & 1) << 6;
    int quad = lane >> 4, lrow = lane & 15;
    u16* out = Mt + (size_t)p * D * D;
    #pragma unroll
    for (int i = 0; i < 4; ++i)
        #pragma unroll
        for (int j = 0; j < 4; ++j) {
            int brow = r0 + wm + i * 16 + quad * 4;
            int col = c0 + wn + j * 16 + lrow;
            #pragma unroll
            for (int r = 0; r < 4; ++r)
                out[(size_t)(brow + r) * D + col] = f2b(acc[i][j][r]);
        }
}

// kZ: Z[l][j] = sum_k xb[l][k] Mt[j][k] + z0[j]   (BM=64 for occupancy)
__global__ __launch_bounds__(256) void kZ_mfma(const u16* __restrict__ xb,
        const u16* __restrict__ Mt, const float* __restrict__ z0,
        u16* __restrict__ Zbuf, const int* __restrict__ sepArr) {
    __shared__ __align__(16) u16 As[64 * 64];
    __shared__ __align__(16) u16 Bs[128 * 64];
    int z = blockIdx.z;
    int p = z >> 3, b = z & 7;
    int sep = sepArr[b];
    int r0 = blockIdx.y * 64;
    if (r0 >= sep) return;
    int c0 = blockIdx.x * 128;
    float4v acc[2][4];
    gemm_core64(xb + (size_t)b * L * D, D, r0,
                Mt + (size_t)p * D * D, D, c0, D, As, Bs, acc);
    int lane = threadIdx.x & 63, wave = threadIdx.x >> 6;
    int wm = (wave >> 1) << 5, wn = (wave & 1) << 6;
    int quad = lane >> 4, lrow = lane & 15;
    const float* z0p = z0 + p * D;
    u16* out = Zbuf + ((size_t)p * NB + b) * 512 * D;
    #pragma unroll
    for (int i = 0; i < 2; ++i)
        #pragma unroll
        for (int j = 0; j < 4; ++j) {
            int brow = r0 + wm + i * 16 + quad * 4;
            int col = c0 + wn + j * 16 + lrow;
            float zb = z0p[col];
            #pragma unroll
            for (int r = 0; r < 4; ++r)
                out[(size_t)(brow + r) * D + col] = f2b(acc[i][j][r] + zb);
        }
}

// kS: merged score kernel, both paths BM=64.
// xi<8: sup path (A=Z0), xi>=8: cmb path (A=Zr,Zc). 32 KB LDS pool.
__global__ __launch_bounds__(256) void kS_mfma(const u16* __restrict__ Zbuf,
        const u16* __restrict__ xb, const float* __restrict__ tcbuf,
        const int* __restrict__ sepArr, u16* __restrict__ ssup,
        u16* __restrict__ scmb) {
    __shared__ __align__(16) u16 smem[16384];   // 32 KB: A0 (4096), A1 (4096), Bs (8192)
    int b = blockIdx.z;
    int sep = sepArr[b];
    int xi = blockIdx.x;
    int tid = threadIdx.x, lane = tid & 63, wave = tid >> 6;
    int quad = lane >> 4, lrow = lane & 15;
    int wm = (wave >> 1) << 5, wn = (wave & 1) << 6;
    int m0 = blockIdx.y * 128;
    if (m0 + 127 <= sep) return;
    u16* A0 = smem;
    u16* A1 = smem + 4096;
    u16* Bs = smem + 8192;
    const u16* X = xb + (size_t)b * L * D;
    if (xi < 8) {
        // ---- sup path ----
        int l0 = xi * 64;
        if (l0 >= sep) return;
        float4v acc[2][4];
        gemm_core64(Zbuf + (size_t)b * 512 * D, D, l0, X, D, m0, D, A0, Bs, acc);
        u16* out = ssup + (size_t)b * 512 * L;
        #pragma unroll
        for (int i = 0; i < 2; ++i)
            #pragma unroll
            for (int j = 0; j < 4; ++j) {
                int brow = l0 + wm + i * 16 + quad * 4;
                int col = m0 + wn + j * 16 + lrow;
                #pragma unroll
                for (int r = 0; r < 4; ++r)
                    out[(size_t)(brow + r) * L + col] = f2b(acc[i][j][r] * SCALE);
            }
        return;
    }
    // ---- cmb path ----
    int l0 = (xi - 8) * 64;
    if (l0 >= sep) return;
    const u16* Zr = Zbuf + ((size_t)2 * NB + b) * 512 * D;
    const u16* Zc = Zbuf + ((size_t)1 * NB + b) * 512 * D;
    float4v ar_[2][4], ac_[2][4];
    #pragma unroll
    for (int i = 0; i < 2; ++i)
        #pragma unroll
        for (int j = 0; j < 4; ++j) { ar_[i][j] = (float4v){0.f,0.f,0.f,0.f}; ac_[i][j] = (float4v){0.f,0.f,0.f,0.f}; }
    for (int k0 = 0; k0 < D; k0 += 64) {
        __syncthreads();
        stage64_async(Zr, D, l0, k0, A0, tid);
        stage64_async(Zr, D, l0, k0 + 32, A0 + 2048, tid);
        stage64_async(Zc, D, l0, k0, A1, tid);
        stage64_async(Zc, D, l0, k0 + 32, A1 + 2048, tid);
        stage128_async(X, D, m0, k0, Bs, tid);
        stage128_async(X, D, m0, k0 + 32, Bs + 4096, tid);
        __syncthreads();
        #pragma unroll
        for (int p = 0; p < 2; ++p) {
            const u16* Arp = A0 + p * 2048;
            const u16* Acp = A1 + p * 2048;
            const u16* Bp  = Bs + p * 4096;
            short8 fr[2], fc[2], fb[4];
            #pragma unroll
            for (int i = 0; i < 2; ++i) {
                fr[i] = *(const short8*)&Arp[(wm + i * 16 + lrow) * 32 + quad * 8];
                fc[i] = *(const short8*)&Acp[(wm + i * 16 + lrow) * 32 + quad * 8];
            }
            #pragma unroll
            for (int j = 0; j < 4; ++j) fb[j] = *(const short8*)&Bp[(wn + j * 16 + lrow) * 32 + quad * 8];
            #pragma unroll
            for (int i = 0; i < 2; ++i)
                #pragma unroll
                for (int j = 0; j < 4; ++j) {
                    ar_[i][j] = MFMA_BF16(fr[i], fb[j], ar_[i][j], 0, 0, 0);
                    ac_[i][j] = MFMA_BF16(fc[i], fb[j], ac_[i][j], 0, 0, 0);
                }
        }
    }
    const float* tc = tcbuf + (size_t)b * 512;
    u16* out = scmb + (size_t)b * 512 * L;
    #pragma unroll
    for (int i = 0; i < 2; ++i)
        #pragma unroll
        for (int j = 0; j < 4; ++j) {
            int brow = l0 + wm + i * 16 + quad * 4;
            int col = m0 + wn + j * 16 + lrow;
            #pragma unroll
            for (int r = 0; r < 4; ++r) {
                float vv = ar_[i][j][r] * SCALE
                         + tanhf((ac_[i][j][r] + tc[brow + r]) * SCALE);
                out[(size_t)(brow + r) * L + col] = f2b(vv);
            }
        }
}

// ---------------- k2bc: fused per-row softmax + column-weight accumulation ----------------
__global__ __launch_bounds__(256) void k2bc(const u16* __restrict__ ssup,
        const u16* __restrict__ scmb, const int* __restrict__ ids,
        const int* __restrict__ padp, const int* __restrict__ sepArr,
        const float* __restrict__ gate, float* __restrict__ csup,
        float* __restrict__ crep, const int* __restrict__ flag) {
    __shared__ float colacc[4][2][1024];   // [wave][mat][col] = 32 KB
    int b = blockIdx.y;
    int sep = sepArr[b];
    int l0 = blockIdx.x * 8;
    int tid = threadIdx.x, lane = tid & 63, w = tid >> 6;
    for (int i = tid; i < 4 * 2 * 1024; i += 256) ((float*)colacc)[i] = 0.f;
    __syncthreads();
    if (l0 < sep) {
        int is64 = flag[1];
        int pad = padp[0];
        unsigned int okmask = 0;
        #pragma unroll
        for (int u = 0; u < 16; ++u) {
            int m = u * 64 + lane;
            bool ok = (m > sep) && (ldid(ids, (size_t)b * L + m, is64) != pad);
            okmask |= (ok ? 1u : 0u) << u;
        }
        for (int t = 0; t < 2; ++t) {
            int l = l0 + w * 2 + t;
            if (l >= sep) continue;
            float g = gate[b * L + l];
            if (g == 0.f) continue;
            const u16* rs = ssup + ((size_t)b * 512 + l) * L;
            const u16* rc = scmb + ((size_t)b * 512 + l) * L;
            float s0[16], s1[16];
            float mx0 = -3.4e38f, mx1 = -3.4e38f;
            #pragma unroll
            for (int u = 0; u < 16; ++u) {
                int m = u * 64 + lane;
                bool ok = (okmask >> u) & 1u;
                s0[u] = ok ? b2f(rs[m]) : NEGV;
                s1[u] = ok ? b2f(rc[m]) : NEGV;
                mx0 = fmaxf(mx0, s0[u]); mx1 = fmaxf(mx1, s1[u]);
            }
            #pragma unroll
            for (int d = 1; d < 64; d <<= 1) {
                mx0 = fmaxf(mx0, __shfl_xor(mx0, d));
                mx1 = fmaxf(mx1, __shfl_xor(mx1, d));
            }
            float e0 = 0.f, e1 = 0.f;
            #pragma unroll
            for (int u = 0; u < 16; ++u) {
                s0[u] = expf(s0[u] - mx0); e0 += s0[u];
                s1[u] = expf(s1[u] - mx1); e1 += s1[u];
            }
            #pragma unroll
            for (int d = 1; d < 64; d <<= 1) {
                e0 += __shfl_xor(e0, d);
                e1 += __shfl_xor(e1, d);
            }
            float i0 = g / fmaxf(e0, 1e-30f), i1 = g / fmaxf(e1, 1e-30f);
            #pragma unroll
            for (int u = 0; u < 16; ++u) {
                int m = u * 64 + lane;
                colacc[w][0][m] += s0[u] * i0;
                colacc[w][1][m] += s1[u] * i1;
            }
        }
    }
    __syncthreads();
    for (int m = tid; m < 1024; m += 256) {
        float a0 = colacc[0][0][m] + colacc[1][0][m] + colacc[2][0][m] + colacc[3][0][m];
        float a1 = colacc[0][1][m] + colacc[1][1][m] + colacc[2][1][m] + colacc[3][1][m];
        if (a0 != 0.f) atomicAdd(&csup[b * L + m], a0);
        if (a1 != 0.f) atomicAdd(&crep[b * L + m], a1);
    }
}

// ---------------- K3: af/w_rep/w_sup weighted sums over xb (bf16) ----------------
__global__ __launch_bounds__(256) void k3(const u16* __restrict__ xb,
        const float* __restrict__ gate, const float* __restrict__ csup,
        const float* __restrict__ crep, float* __restrict__ af,
        float* __restrict__ wrep, float* __restrict__ wsup) {
    int b = blockIdx.y, c = blockIdx.x;
    int tid = threadIdx.x;
    float a0 = 0.f, a1 = 0.f, a2 = 0.f;
    float r0 = 0.f, r1 = 0.f, r2 = 0.f;
    float q0 = 0.f, q1 = 0.f, q2 = 0.f;
    for (int mm = 0; mm < 16; ++mm) {
        int m = c * 16 + mm;
        float wg = gate[b * L + m], wr = crep[b * L + m], wq = csup[b * L + m];
        if (wg == 0.f && wr == 0.f && wq == 0.f) continue;
        size_t base = ((size_t)b * L + m) * D;
        float x0 = b2f(xb[base + tid]);
        float x1 = b2f(xb[base + tid + 256]);
        float x2 = b2f(xb[base + tid + 512]);
        a0 += wg * x0; a1 += wg * x1; a2 += wg * x2;
        r0 += wr * x0; r1 += wr * x1; r2 += wr * x2;
        q0 += wq * x0; q1 += wq * x1; q2 += wq * x2;
    }
    atomicAdd(&af[b * D + tid], a0); atomicAdd(&af[b * D + tid + 256], a1); atomicAdd(&af[b * D + tid + 512], a2);
    atomicAdd(&wrep[b * D + tid], r0); atomicAdd(&wrep[b * D + tid + 256], r1); atomicAdd(&wrep[b * D + tid + 512], r2);
    atomicAdd(&wsup[b * D + tid], q0); atomicAdd(&wsup[b * D + tid + 256], q1); atomicAdd(&wsup[b * D + tid + 512], q2);
}

// ---------------- kh1: hacc += fused @ Wf1 (split-K) ----------------
template<int F32> __device__ void kh1_body(const float* af, const float* wrep,
        const float* wsup, const void* Wf1, float* hacc, float* fs) {
    int tid = threadIdx.x;
    int c0 = blockIdx.x * 128, k0 = blockIdx.y * 144;
    for (int e = tid; e < 8 * 144; e += 256) {
        int b = e / 144, kk = e - b * 144;
        int k = k0 + kk;
        float v = (k < D) ? af[b * D + k] : (k < 2 * D) ? wrep[b * D + k - D]
                                                        : wsup[b * D + k - 2 * D];
        fs[b * 144 + kk] = v;
    }
    __syncthreads();
    int col = c0 + (tid & 127);
    int kg = tid >> 7;
    float acc[NB];
    #pragma unroll
    for (int b = 0; b < NB; ++b) acc[b] = 0.f;
    #pragma unroll 4
    for (int r = 0; r < 72; ++r) {
        int kk = kg * 72 + r;
        float w = ld1<F32>(Wf1, (size_t)(k0 + kk) * D + col);
        #pragma unroll
        for (int b = 0; b < NB; ++b) acc[b] += fs[b * 144 + kk] * w;
    }
    #pragma unroll
    for (int b = 0; b < NB; ++b) atomicAdd(&hacc[b * D + col], acc[b]);
}
__global__ __launch_bounds__(256) void kh1(const float* af, const float* wrep,
        const float* wsup, const void* Wf1, float* hacc, const int* flag) {
    __shared__ float fs[8 * 144];
    if (flag[0]) kh1_body<1>(af, wrep, wsup, Wf1, hacc, fs);
    else         kh1_body<0>(af, wrep, wsup, Wf1, hacc, fs);
}

// ---------------- kh2: oacc += relu(hacc+bf1) @ Wf2 (split-K) ----------------
template<int F32> __device__ void kh2_body(const float* hacc, const void* bf1,
        const void* Wf2, float* oacc, float* hsl) {
    int tid = threadIdx.x;
    int c0 = blockIdx.x * 128, k0 = blockIdx.y * 96;
    for (int e = tid; e < 8 * 96; e += 256) {
        int b = e / 96, kk = e - b * 96;
        int k = k0 + kk;
        hsl[b * 96 + kk] = fmaxf(hacc[b * D + k] + ld1<F32>(bf1, k), 0.f);
    }
    __syncthreads();
    int col = c0 + (tid & 127);
    int kg = tid >> 7;
    float acc[NB];
    #pragma unroll
    for (int b = 0; b < NB; ++b) acc[b] = 0.f;
    #pragma unroll 4
    for (int r = 0; r < 48; ++r) {
        int kk = kg * 48 + r;
        float w = ld1<F32>(Wf2, (size_t)(k0 + kk) * D + col);
        #pragma unroll
        for (int b = 0; b < NB; ++b) acc[b] += hsl[b * 96 + kk] * w;
    }
    #pragma unroll
    for (int b = 0; b < NB; ++b) atomicAdd(&oacc[b * D + col], acc[b]);
}
__global__ __launch_bounds__(256) void kh2(const float* hacc, const void* bf1,
        const void* Wf2, float* oacc, const int* flag) {
    __shared__ float hsl[8 * 96];
    if (flag[0]) kh2_body<1>(hacc, bf1, Wf2, oacc, hsl);
    else         kh2_body<0>(hacc, bf1, Wf2, oacc, hsl);
}

// ---------------- kln: out = LN(oacc + bf2) * gamma + beta ----------------
template<int F32> __device__ void kln_body(const float* oacc, const void* bf2,
        const void* gamma, const void* beta, void* out, float* red) {
    int b = blockIdx.x, tid = threadIdx.x;
    float o[3];
    #pragma unroll
    for (int u = 0; u < 3; ++u) {
        int i = tid + u * 256;
        o[u] = oacc[b * D + i] + ld1<F32>(bf2, i);
    }
    red[tid] = o[0] + o[1] + o[2]; __syncthreads();
    for (int s = 128; s > 0; s >>= 1) { if (tid < s) red[tid] += red[tid + s]; __syncthreads(); }
    float mu = red[0] / (float)D; __syncthreads();
    float vs = 0.f;
    #pragma unroll
    for (int u = 0; u < 3; ++u) vs += (o[u] - mu) * (o[u] - mu);
    red[tid] = vs; __syncthreads();
    for (int s = 128; s > 0; s >>= 1) { if (tid < s) red[tid] += red[tid + s]; __syncthreads(); }
    float var = red[0] / (float)D;
    float rstd = 1.0f / sqrtf(var + 1e-5f);
    #pragma unroll
    for (int u = 0; u < 3; ++u) {
        int i = tid + u * 256;
        float v = (o[u] - mu) * rstd * ld1<F32>(gamma, i) + ld1<F32>(beta, i);
        if (F32) ((float*)out)[b * D + i] = v;
        else     ((u16*)out)[b * D + i] = f2b(v);
    }
}
__global__ __launch_bounds__(256) void kln(const float* oacc, const void* bf2,
        const void* gamma, const void* beta, void* out, const int* flag) {
    __shared__ float red[256];
    if (flag[0]) kln_body<1>(oacc, bf2, gamma, beta, out, red);
    else         kln_body<0>(oacc, bf2, gamma, beta, out, red);
}

extern "C" void kernel_launch(void* const* d_in, const int* in_sizes, int n_in,
                              void* d_out, int out_size, void* d_ws, size_t ws_size,
                              hipStream_t stream) {
    const void* x    = d_in[0];
    const int* ids   = (const int*)d_in[1];
    const int* padp  = (const int*)d_in[2];
    const void* Wa   = d_in[3];
    const void* ba   = d_in[4];
    PP pp;
    pp.W[0] = d_in[5];  pp.b[0] = d_in[6];    // qs
    pp.W[1] = d_in[7];  pp.b[1] = d_in[8];    // ks
    pp.W[2] = d_in[9];  pp.b[2] = d_in[10];   // qc
    pp.W[3] = d_in[11]; pp.b[3] = d_in[12];   // kc
    pp.W[4] = d_in[13]; pp.b[4] = d_in[14];   // qr
    pp.W[5] = d_in[15]; pp.b[5] = d_in[16];   // kr
    const void* Wf1 = d_in[17]; const void* bf1 = d_in[18];
    const void* Wf2 = d_in[19]; const void* bf2 = d_in[20];
    const void* gamma = d_in[21]; const void* beta = d_in[22];

    char* ws = (char*)d_ws;
    int*   flag   = (int*)(ws + WS_FLAG);
    int*   sepArr = (int*)(ws + WS_SEP);
    float* c0   = (float*)(ws + WS_C0);
    float* z0   = (float*)(ws + WS_Z0);
    float* w1   = (float*)(ws + WS_W1);
    float* gate = (float*)(ws + WS_GATE);
    float* csup = (float*)(ws + WS_CSUP);
    float* crep = (float*)(ws + WS_CREP);
    float* af   = (float*)(ws + WS_AF);
    float* wrep = (float*)(ws + WS_WREP);
    float* wsup = (float*)(ws + WS_WSUP);
    float* hacc = (float*)(ws + WS_HACC);
    float* oacc = (float*)(ws + WS_OACC);
    float* alog = (float*)(ws + WS_ALOG);
    float* tbuf = (float*)(ws + WS_T);
    u16* xb   = (u16*)(ws + WS_XB);
    u16* Zbuf = (u16*)(ws + WS_Z);
    u16* Wb   = (u16*)(ws + WS_WB);
    u16* Mt   = (u16*)(ws + WS_M);
    u16* ssup = (u16*)(ws + WS_SSUP);
    u16* scmb = (u16*)(ws + WS_SCMB);

    kdetect<<<dim3(1), dim3(128), 0, stream>>>(x, ids, flag);
    kbias_row<<<dim3(12, 5), dim3(256), 0, stream>>>(pp, z0, w1, c0, flag);
    kx<<<dim3(1984), dim3(256), 0, stream>>>(x, pp, Wa, ba, w1, c0, xb, Wb, alog, tbuf, flag);
    k0b<<<dim3(NB), dim3(256), 0, stream>>>(ids, padp, alog, gate, sepArr,
                                            af, wrep, wsup, hacc, oacc, csup, crep, flag);
    kM_mfma<<<dim3(6, 6, 3), dim3(256), 0, stream>>>(Wb, Mt);
    kZ_mfma<<<dim3(6, 8, 24), dim3(256), 0, stream>>>(xb, Mt, z0, Zbuf, sepArr);
    kS_mfma<<<dim3(16, 8, NB), dim3(256), 0, stream>>>(Zbuf, xb, tbuf, sepArr, ssup, scmb);
    k2bc<<<dim3(64, NB), dim3(256), 0, stream>>>(ssup, scmb, ids, padp, sepArr,
                                                 gate, csup, crep, flag);
    k3<<<dim3(64, NB), dim3(256), 0, stream>>>(xb, gate, csup, crep, af, wrep, wsup);
    kh1<<<dim3(6, 16), dim3(256), 0, stream>>>(af, wrep, wsup, Wf1, hacc, flag);
    kh2<<<dim3(6, 8), dim3(256), 0, stream>>>(hacc, bf1, Wf2, oacc, flag);
    kln<<<dim3(NB), dim3(256), 0, stream>>>(oacc, bf2, gamma, beta, d_out, flag);
}